// Round 1
// baseline (554.061 us; speedup 1.0000x reference)
//
#include <hip/hip_runtime.h>
#include <math.h>

#define NSAMP 32768
#define FS_F 44100.0f
#define PI_F 3.14159265358979323846f

struct BParams {
  float alpha, alpha_p;
  float c0, c1, c2;
  int Di;
  float lc, lm, lp;
};

__device__ inline float sigmoidf_(float x) { return 1.0f / (1.0f + expf(-x)); }

__device__ inline BParams compute_params(int b, const float* __restrict__ pitch,
                                         const float* __restrict__ w1,
                                         const float* __restrict__ b1,
                                         const float* __restrict__ w2,
                                         const float* __restrict__ b2) {
  BParams P;
  float p = pitch[b];
  float h[16];
#pragma unroll
  for (int i = 0; i < 16; ++i) {
    float v = fmaf(p, w1[i], b1[i]);
    h[i] = v > 0.0f ? v : 0.0f;
  }
  float m[3];
#pragma unroll
  for (int j = 0; j < 3; ++j) {
    float acc = b2[j];
#pragma unroll
    for (int i = 0; i < 16; ++i) acc = fmaf(h[i], w2[j * 16 + i], acc);
    m[j] = acc;
  }
  P.lc = fminf(fmaxf(m[0], -2.0f), 2.5f);
  P.lm = fminf(fmaxf(m[1], -2.5f), 0.0f);
  P.lp = fminf(fmaxf(m[2], -4.0f), 4.0f);
  float g = 0.999f * sigmoidf_(P.lc);
  float s = sigmoidf_(P.lm);
  float f0 = fmaxf(p, 60.0f);
  float D = fminf(fmaxf(FS_F / f0, 2.0f), 735.0f);
  int Di = (int)floorf(D);
  float fr = D - (float)Di;
  P.Di = Di;
  P.c0 = g * (1.0f - s) * (1.0f - fr);
  P.c1 = g * ((1.0f - s) * fr + s * (1.0f - fr));
  P.c2 = g * s * fr;
  float mult = fminf(fmaxf(2.0f + 6.0f * (f0 - 60.0f) / 600.0f, 2.0f), 8.0f);
  float cutoff = fminf(2.0f * PI_F * f0 * mult / FS_F, PI_F * 0.9f);
  P.alpha = 1.0f - expf(-cutoff);
  float cpost = fminf(PI_F * sigmoidf_(P.lp), PI_F * 0.99f);
  P.alpha_p = 1.0f - expf(-cpost);
  return P;
}

// Exact block-parallel one-pole IIR: y[n] = scale*x[n] + c*y[n-1], y[-1]=0.
// 256 threads, segments of 128; thread-local (P,S) affine compose, thread-0
// serial scan over 256 pairs, then re-run with correct seed.
__device__ inline void lpc_scan(const float* __restrict__ in, float* __restrict__ out,
                                float scale, float c, int t,
                                float* sP, float* sS, float* sV) {
  const int SEG = NSAMP / 256;  // 128
  const float* x = in + t * SEG;
  float Pp = 1.0f, S = 0.0f;
#pragma unroll 4
  for (int i = 0; i < SEG; ++i) {
    S = fmaf(c, S, scale * x[i]);
    Pp *= c;
  }
  sP[t] = Pp;
  sS[t] = S;
  __syncthreads();
  if (t == 0) {
    float v = 0.0f;
    for (int i = 0; i < 256; ++i) {
      sV[i] = v;
      v = fmaf(sP[i], v, sS[i]);
    }
  }
  __syncthreads();
  float v = sV[t];
  float* y = out + t * SEG;
#pragma unroll 4
  for (int i = 0; i < SEG; ++i) {
    v = fmaf(c, v, scale * x[i]);
    y[i] = v;
  }
  __syncthreads();  // make `out` (global) visible block-wide before next phase
}

// One block per batch: preLP -> Karplus-Strong chunked loop -> postLP.
__global__ void __launch_bounds__(256) synth_kernel(
    const float* __restrict__ exc, const float* __restrict__ pitch,
    const float* __restrict__ w1, const float* __restrict__ b1,
    const float* __restrict__ w2, const float* __restrict__ b2,
    const float* __restrict__ eg, float* __restrict__ buf0,
    float* __restrict__ buf1, float* __restrict__ out_scalars) {
  const int b = blockIdx.x;
  const int t = threadIdx.x;
  __shared__ float ring[2048];
  __shared__ float sP[256], sS[256], sV[256];

  BParams P = compute_params(b, pitch, w1, b1, w2, b2);

  if (b == 0 && t == 0) {
    float slc = 0.0f, slm = 0.0f, slp = 0.0f;
    for (int i = 0; i < 8; ++i) {
      BParams Q = compute_params(i, pitch, w1, b1, w2, b2);
      slc += Q.lc;
      slm += Q.lm;
      slp += Q.lp;
    }
    out_scalars[0] = slc / 8.0f;
    out_scalars[1] = slm / 8.0f;
    out_scalars[2] = slp / 8.0f;
  }

  for (int i = t; i < 2048; i += 256) ring[i] = 0.0f;

  // phase 1: pre-LP: y = (exc*eg*alpha) + (1-alpha)*y_prev  : exc -> buf0
  lpc_scan(exc + b * NSAMP, buf0 + b * NSAMP, eg[0] * P.alpha, 1.0f - P.alpha, t,
           sP, sS, sV);

  // phase 2: KS. Chunk of Di samples is data-parallel (taps at lag >= Di).
  const float* x = buf0 + b * NSAMP;
  float* y = buf1 + b * NSAMP;
  const int Di = P.Di;
  const float c0 = P.c0, c1 = P.c1, c2 = P.c2;
  const int C = Di;  // chunk size, 66..735 -> <= 3 samples/thread at 256 thr

  float xr[3];
#pragma unroll
  for (int k = 0; k < 3; ++k) {
    int i = t + k * 256;
    xr[k] = (i < C) ? x[i] : 0.0f;
  }

  int n0 = 0;
  while (n0 < NSAMP) {
    int rem = NSAMP - n0;
    int Ccur = C < rem ? C : rem;
    float yv[3];
#pragma unroll
    for (int k = 0; k < 3; ++k) {
      int i = t + k * 256;
      if (i < Ccur) {
        int n = n0 + i;
        float v1 = ring[(n - Di) & 2047];
        float v2 = ring[(n - Di - 1) & 2047];
        float v3 = ring[(n - Di - 2) & 2047];
        yv[k] = fmaf(c0, v1, fmaf(c1, v2, fmaf(c2, v3, xr[k])));
      }
    }
#pragma unroll
    for (int k = 0; k < 3; ++k) {
      int i = t + k * 256;
      if (i < Ccur) {
        ring[(n0 + i) & 2047] = yv[k];
        y[n0 + i] = yv[k];
      }
    }
    n0 += Ccur;
    // prefetch next chunk's excitation (overlaps this chunk's LDS latency)
#pragma unroll
    for (int k = 0; k < 3; ++k) {
      int i = t + k * 256;
      int n = n0 + i;
      xr[k] = (i < C && n < NSAMP) ? x[n] : 0.0f;
    }
    __syncthreads();
  }

  // phase 3: post-LP: buf1 -> buf0
  lpc_scan(buf1 + b * NSAMP, buf0 + b * NSAMP, P.alpha_p, 1.0f - P.alpha_p, t, sP,
           sS, sV);
}

// One block per (band, batch). Exact 2x2 affine scan of the 2-pole resonator;
// accumulate gain*y into zeroed d_out via atomics.
__global__ void __launch_bounds__(256) body_kernel(const float* __restrict__ xin,
                                                   float* __restrict__ out,
                                                   const float* __restrict__ gains) {
  const int k = blockIdx.x;
  const int b = blockIdx.y;
  const int t = threadIdx.x;
  const int SEG = NSAMP / 256;

  float fc = (float)(80.0 * pow(100.0, (double)k / 23.0));
  float w = 2.0f * PI_F * fc / FS_F;
  float r = expf(-PI_F * fc / (10.0f * FS_F));
  float a1 = -2.0f * r * cosf(w);
  float a2 = r * r;
  float b0 = 1.0f - r;
  float gain = gains[k];

  const float* x = xin + b * NSAMP + t * SEG;

  // pass 1: segment as affine map on state (y[n-1], y[n-2]): s_out = A s_in + cv
  float A00 = 1.0f, A01 = 0.0f, A10 = 0.0f, A11 = 1.0f, cv0 = 0.0f, cv1 = 0.0f;
#pragma unroll 4
  for (int i = 0; i < SEG; ++i) {
    float xi = x[i];
    float n00 = -a1 * A00 - a2 * A10;
    float n01 = -a1 * A01 - a2 * A11;
    A10 = A00;
    A11 = A01;
    A00 = n00;
    A01 = n01;
    float nc0 = fmaf(b0, xi, -a1 * cv0 - a2 * cv1);
    cv1 = cv0;
    cv0 = nc0;
  }
  __shared__ float sA0[256], sA1[256], sA2[256], sA3[256];
  __shared__ float sc0[256], sc1[256];
  __shared__ float sv0[256], sv1[256];
  sA0[t] = A00; sA1[t] = A01; sA2[t] = A10; sA3[t] = A11;
  sc0[t] = cv0; sc1[t] = cv1;
  __syncthreads();
  if (t == 0) {
    float v0 = 0.0f, v1 = 0.0f;
    for (int i = 0; i < 256; ++i) {
      sv0[i] = v0;
      sv1[i] = v1;
      float nv0 = sA0[i] * v0 + sA1[i] * v1 + sc0[i];
      float nv1 = sA2[i] * v0 + sA3[i] * v1 + sc1[i];
      v0 = nv0;
      v1 = nv1;
    }
  }
  __syncthreads();
  float y1 = sv0[t], y2 = sv1[t];
  float* o = out + b * NSAMP + t * SEG;
#pragma unroll 4
  for (int i = 0; i < SEG; ++i) {
    float yv = fmaf(b0, x[i], -a1 * y1 - a2 * y2);
    y2 = y1;
    y1 = yv;
    atomicAdd(&o[i], gain * yv);
  }
}

extern "C" void kernel_launch(void* const* d_in, const int* in_sizes, int n_in,
                              void* d_out, int out_size, void* d_ws, size_t ws_size,
                              hipStream_t stream) {
  const float* exc = (const float*)d_in[0];
  const float* pitch = (const float*)d_in[1];
  const float* w1 = (const float*)d_in[2];
  const float* b1 = (const float*)d_in[3];
  const float* w2 = (const float*)d_in[4];
  const float* b2 = (const float*)d_in[5];
  const float* eg = (const float*)d_in[6];
  const float* bg = (const float*)d_in[7];
  float* out = (float*)d_out;
  float* buf0 = (float*)d_ws;               // 8*32768 floats: exc_f, then y2
  float* buf1 = buf0 + 8 * NSAMP;           // 8*32768 floats: KS output

  // harness poisons d_out with 0xAA; body accumulates via atomics -> zero it
  hipMemsetAsync(d_out, 0, (size_t)(8 * NSAMP) * sizeof(float), stream);

  hipLaunchKernelGGL(synth_kernel, dim3(8), dim3(256), 0, stream, exc, pitch, w1,
                     b1, w2, b2, eg, buf0, buf1, out + 8 * NSAMP);
  hipLaunchKernelGGL(body_kernel, dim3(24, 8), dim3(256), 0, stream, buf0, out,
                     bg);
}

// Round 2
// 506.845 us; speedup vs baseline: 1.0932x; 1.0932x over previous
//
#include <hip/hip_runtime.h>
#include <math.h>

#define NSAMP 32768
#define FS_F 44100.0f
#define PI_F 3.14159265358979323846f
#define NK 12  // ceil(735/64): max KS chunk regs per lane

struct BParams {
  float alpha, alpha_p;
  float fr, g, s;
  int Di;
  float lc, lm, lp;
};

__device__ inline float sigmoidf_(float x) { return 1.0f / (1.0f + expf(-x)); }

__device__ inline BParams compute_params(int b, const float* __restrict__ pitch,
                                         const float* __restrict__ w1,
                                         const float* __restrict__ b1,
                                         const float* __restrict__ w2,
                                         const float* __restrict__ b2) {
  BParams P;
  float p = pitch[b];
  float h[16];
#pragma unroll
  for (int i = 0; i < 16; ++i) {
    float v = fmaf(p, w1[i], b1[i]);
    h[i] = v > 0.0f ? v : 0.0f;
  }
  float m[3];
#pragma unroll
  for (int j = 0; j < 3; ++j) {
    float acc = b2[j];
#pragma unroll
    for (int i = 0; i < 16; ++i) acc = fmaf(h[i], w2[j * 16 + i], acc);
    m[j] = acc;
  }
  P.lc = fminf(fmaxf(m[0], -2.0f), 2.5f);
  P.lm = fminf(fmaxf(m[1], -2.5f), 0.0f);
  P.lp = fminf(fmaxf(m[2], -4.0f), 4.0f);
  P.g = 0.999f * sigmoidf_(P.lc);
  P.s = sigmoidf_(P.lm);
  float f0 = fmaxf(p, 60.0f);
  float D = fminf(fmaxf(FS_F / f0, 2.0f), 735.0f);
  int Di = (int)floorf(D);
  P.fr = D - (float)Di;
  P.Di = Di;
  float mult = fminf(fmaxf(2.0f + 6.0f * (f0 - 60.0f) / 600.0f, 2.0f), 8.0f);
  float cutoff = fminf(2.0f * PI_F * f0 * mult / FS_F, PI_F * 0.9f);
  P.alpha = 1.0f - expf(-cutoff);
  float cpost = fminf(PI_F * sigmoidf_(P.lp), PI_F * 0.99f);
  P.alpha_p = 1.0f - expf(-cpost);
  return P;
}

// lane helpers (wave64, all lanes active)
__device__ inline float rl63(float v) {
  return __int_as_float(__builtin_amdgcn_readlane(__float_as_int(v), 63));
}
__device__ inline float rlv(float v, int l) {
  return __int_as_float(__builtin_amdgcn_readlane(__float_as_int(v), l));
}
// whole-wave shift right by 1; lane 0 takes `bnd` (uniform carry-in)
__device__ inline float shr1(float v, float bnd) {
  return __int_as_float(__builtin_amdgcn_update_dpp(
      __float_as_int(bnd), __float_as_int(v), 0x138 /*wave_shr:1*/, 0xf, 0xf,
      false));
}

// Exact block-parallel one-pole IIR: y[n] = scale*x[n] + c*y[n-1], y[-1]=0.
__device__ inline void lpc_scan(const float* __restrict__ in, float* __restrict__ out,
                                float scale, float c, int t,
                                float* sP, float* sS, float* sV) {
  const int SEG = NSAMP / 256;  // 128
  const float* x = in + t * SEG;
  float Pp = 1.0f, S = 0.0f;
#pragma unroll 4
  for (int i = 0; i < SEG; ++i) {
    S = fmaf(c, S, scale * x[i]);
    Pp *= c;
  }
  sP[t] = Pp;
  sS[t] = S;
  __syncthreads();
  if (t == 0) {
    float v = 0.0f;
    for (int i = 0; i < 256; ++i) {
      sV[i] = v;
      v = fmaf(sP[i], v, sS[i]);
    }
  }
  __syncthreads();
  float v = sV[t];
  float* y = out + t * SEG;
#pragma unroll 4
  for (int i = 0; i < SEG; ++i) {
    v = fmaf(c, v, scale * x[i]);
    y[i] = v;
  }
  __syncthreads();  // drains stores (vmcnt) -> `out` visible block-wide
}

// One block per batch: preLP -> KS (wave 0, register-only, barrier-free) -> postLP.
__global__ void __launch_bounds__(256) synth_kernel(
    const float* __restrict__ exc, const float* __restrict__ pitch,
    const float* __restrict__ w1, const float* __restrict__ b1,
    const float* __restrict__ w2, const float* __restrict__ b2,
    const float* __restrict__ eg, float* __restrict__ buf0,
    float* __restrict__ buf1, float* __restrict__ out_scalars) {
  const int b = blockIdx.x;
  const int t = threadIdx.x;
  __shared__ float sP[256], sS[256], sV[256];

  BParams P = compute_params(b, pitch, w1, b1, w2, b2);

  if (b == 0 && t == 0) {
    float slc = 0.0f, slm = 0.0f, slp = 0.0f;
    for (int i = 0; i < 8; ++i) {
      BParams Q = compute_params(i, pitch, w1, b1, w2, b2);
      slc += Q.lc;
      slm += Q.lm;
      slp += Q.lp;
    }
    out_scalars[0] = slc / 8.0f;
    out_scalars[1] = slm / 8.0f;
    out_scalars[2] = slp / 8.0f;
  }

  // phase 1: pre-LP: exc -> buf0
  lpc_scan(exc + b * NSAMP, buf0 + b * NSAMP, eg[0] * P.alpha, 1.0f - P.alpha, t,
           sP, sS, sV);

  // phase 2: KS on wave 0 only. Chunk size == Di, so chunk j's taps are
  // exactly chunk j-1's samples at offsets i, i-1, i-2 -> previous chunk
  // lives in registers; shifts via DPP wave_shr:1 with readlane carries.
  // Uses z1(n) == z(n-1) to need only two shifted streams.
  if (t < 64) {
    const float* x = buf0 + b * NSAMP;
    float* yo = buf1 + b * NSAMP;
    const int C = P.Di;            // 66..735
    const float fr = P.fr;
    const float omfr = 1.0f - fr;
    const float w0 = P.g * (1.0f - P.s);
    const float w1c = P.g * P.s;
    const int llast = (C - 1) & 63;
    const int klast = (C - 1) >> 6;  // >=1 since C>=66

    float yprev[NK], xr[NK], xn1[NK], xn2[NK];
#pragma unroll
    for (int k = 0; k < NK; ++k) yprev[k] = 0.0f;
#pragma unroll
    for (int k = 0; k < NK; ++k) {
      int i = t + 64 * k;
      xr[k] = (i < C) ? x[i] : 0.0f;
      xn1[k] = (i < C && C + i < NSAMP) ? x[C + i] : 0.0f;
      xn2[k] = (i < C && 2 * C + i < NSAMP) ? x[2 * C + i] : 0.0f;
    }
    float e1 = 0.0f;     // y[n0 - Di - 1]  (last sample of chunk j-2)
    float zlast = 0.0f;  // z(n0 - 1)       (last z of chunk j-1)
    int n0 = 0;
    while (n0 < NSAMP) {
      float z[NK], y[NK];
      // z(i) = (1-fr)*yprev(i) + fr*yprev(i-1)
#pragma unroll
      for (int k = 0; k < NK; ++k) {
        if (64 * k < C) {
          float bnd = (k == 0) ? e1 : rl63(yprev[k - 1]);
          float b2 = shr1(yprev[k], bnd);
          z[k] = fmaf(fr, b2, omfr * yprev[k]);
        }
      }
      // y(i) = x(i) + w0*z(i) + w1*z(i-1)
#pragma unroll
      for (int k = 0; k < NK; ++k) {
        if (64 * k < C) {
          float bz = (k == 0) ? zlast : rl63(z[k - 1]);
          float zsh = shr1(z[k], bz);
          y[k] = fmaf(w0, z[k], fmaf(w1c, zsh, xr[k]));
        }
      }
      // store (fire-and-forget; drained by the __syncthreads after KS)
#pragma unroll
      for (int k = 0; k < NK; ++k) {
        if (64 * k < C) {
          int i = t + 64 * k;
          int n = n0 + i;
          if (i < C && n < NSAMP) yo[n] = y[k];
        }
      }
      // carries for next chunk (uniform register select)
      float e1n = e1, zln = zlast;
#pragma unroll
      for (int k = 0; k < NK; ++k) {
        if (k == klast) {
          e1n = rlv(yprev[k], llast);  // y[n0-1] = yprev(C-1)
          zln = rlv(z[k], llast);      // z(n0+C-1)
        }
      }
      e1 = e1n;
      zlast = zln;
#pragma unroll
      for (int k = 0; k < NK; ++k) {
        if (64 * k < C) yprev[k] = y[k];
      }
      // rotate prefetch pipeline (depth 2) and issue next load
#pragma unroll
      for (int k = 0; k < NK; ++k) {
        xr[k] = xn1[k];
        xn1[k] = xn2[k];
      }
      int m = n0 + 3 * C;
#pragma unroll
      for (int k = 0; k < NK; ++k) {
        int i = t + 64 * k;
        xn2[k] = (i < C && m + i < NSAMP) ? x[m + i] : 0.0f;
      }
      n0 += C;
    }
  }
  __syncthreads();  // drain wave-0 stores; buf1 visible block-wide

  // phase 3: post-LP: buf1 -> buf0
  lpc_scan(buf1 + b * NSAMP, buf0 + b * NSAMP, P.alpha_p, 1.0f - P.alpha_p, t, sP,
           sS, sV);
}

// ---- body: per-(band,batch) 2-pole resonator via exact 2x2 affine scan ----
__device__ inline void body_coeffs(int k, float& a1, float& a2, float& b0) {
  float fc = (float)(80.0 * pow(100.0, (double)k / 23.0));
  float w = 2.0f * PI_F * fc / FS_F;
  float r = expf(-PI_F * fc / (10.0f * FS_F));
  a1 = -2.0f * r * cosf(w);
  a2 = r * r;
  b0 = 1.0f - r;
}

template <bool USE_ATOMIC>
__device__ inline void body_impl(const float* __restrict__ xin,
                                 float* __restrict__ dst,
                                 const float* __restrict__ gains) {
  const int k = blockIdx.x;
  const int b = blockIdx.y;
  const int t = threadIdx.x;
  const int SEG = NSAMP / 256;

  float a1, a2, b0;
  body_coeffs(k, a1, a2, b0);
  float gain = gains[k];

  const float* x = xin + b * NSAMP + t * SEG;

  float A00 = 1.0f, A01 = 0.0f, A10 = 0.0f, A11 = 1.0f, cv0 = 0.0f, cv1 = 0.0f;
#pragma unroll 4
  for (int i = 0; i < SEG; ++i) {
    float xi = x[i];
    float n00 = -a1 * A00 - a2 * A10;
    float n01 = -a1 * A01 - a2 * A11;
    A10 = A00;
    A11 = A01;
    A00 = n00;
    A01 = n01;
    float nc0 = fmaf(b0, xi, -a1 * cv0 - a2 * cv1);
    cv1 = cv0;
    cv0 = nc0;
  }
  __shared__ float sA0[256], sA1[256], sA2[256], sA3[256];
  __shared__ float sc0[256], sc1[256];
  __shared__ float sv0[256], sv1[256];
  sA0[t] = A00; sA1[t] = A01; sA2[t] = A10; sA3[t] = A11;
  sc0[t] = cv0; sc1[t] = cv1;
  __syncthreads();
  if (t == 0) {
    float v0 = 0.0f, v1 = 0.0f;
    for (int i = 0; i < 256; ++i) {
      sv0[i] = v0;
      sv1[i] = v1;
      float nv0 = sA0[i] * v0 + sA1[i] * v1 + sc0[i];
      float nv1 = sA2[i] * v0 + sA3[i] * v1 + sc1[i];
      v0 = nv0;
      v1 = nv1;
    }
  }
  __syncthreads();
  float y1 = sv0[t], y2 = sv1[t];
#pragma unroll 4
  for (int i = 0; i < SEG; ++i) {
    float yv = fmaf(b0, x[i], -a1 * y1 - a2 * y2);
    y2 = y1;
    y1 = yv;
    if (USE_ATOMIC) {
      atomicAdd(&dst[b * NSAMP + t * SEG + i], gain * yv);
    } else {
      dst[((size_t)k * 8 + b) * NSAMP + t * SEG + i] = gain * yv;
    }
  }
}

__global__ void __launch_bounds__(256) body_part(const float* __restrict__ xin,
                                                 float* __restrict__ part,
                                                 const float* __restrict__ gains) {
  body_impl<false>(xin, part, gains);
}

__global__ void __launch_bounds__(256) body_atomic(const float* __restrict__ xin,
                                                   float* __restrict__ out,
                                                   const float* __restrict__ gains) {
  body_impl<true>(xin, out, gains);
}

__global__ void __launch_bounds__(256) reduce_kernel(const float* __restrict__ part,
                                                     float* __restrict__ out) {
  int idx = blockIdx.x * 256 + threadIdx.x;  // b*NSAMP + n, 0..262143
  float s = 0.0f;
#pragma unroll
  for (int k = 0; k < 24; ++k) s += part[(size_t)k * 8 * NSAMP + idx];
  out[idx] = s;
}

extern "C" void kernel_launch(void* const* d_in, const int* in_sizes, int n_in,
                              void* d_out, int out_size, void* d_ws, size_t ws_size,
                              hipStream_t stream) {
  const float* exc = (const float*)d_in[0];
  const float* pitch = (const float*)d_in[1];
  const float* w1 = (const float*)d_in[2];
  const float* b1 = (const float*)d_in[3];
  const float* w2 = (const float*)d_in[4];
  const float* b2 = (const float*)d_in[5];
  const float* eg = (const float*)d_in[6];
  const float* bg = (const float*)d_in[7];
  float* out = (float*)d_out;
  float* buf0 = (float*)d_ws;              // 8*32768: exc_f, then post-LP string
  float* buf1 = buf0 + 8 * NSAMP;          // 8*32768: KS output
  float* part = buf1 + 8 * NSAMP;          // 24*8*32768: per-band partials

  hipLaunchKernelGGL(synth_kernel, dim3(8), dim3(256), 0, stream, exc, pitch, w1,
                     b1, w2, b2, eg, buf0, buf1, out + 8 * NSAMP);

  size_t need = (size_t)(16 + 24 * 8) * NSAMP * sizeof(float);
  if (ws_size >= need) {
    hipLaunchKernelGGL(body_part, dim3(24, 8), dim3(256), 0, stream, buf0, part,
                       bg);
    hipLaunchKernelGGL(reduce_kernel, dim3(8 * NSAMP / 256), dim3(256), 0, stream,
                       part, out);
  } else {
    hipMemsetAsync(d_out, 0, (size_t)(8 * NSAMP) * sizeof(float), stream);
    hipLaunchKernelGGL(body_atomic, dim3(24, 8), dim3(256), 0, stream, buf0, out,
                       bg);
  }
}